// Round 8
// baseline (1005.785 us; speedup 1.0000x reference)
//
#include <hip/hip_runtime.h>

#define B_   256
#define NIN_ 512
#define T_   256
#define H1_  512
#define H2_  512
#define OUT_ 128

typedef __attribute__((ext_vector_type(4))) int i32x4;
typedef __attribute__((address_space(1))) const unsigned int* gl_cu;
typedef __attribute__((address_space(3))) unsigned int* ls_u;

// ---------------------------------------------------------------------------
// Per-tensor absmax, parallel: 64 blocks per tensor, atomicMax on uint bits
// (valid: all values are fabs() >= 0; IEEE non-negative floats order as uints).
// smax[] zeroed by hipMemsetAsync.  Max is order-independent -> same scale.
// ---------------------------------------------------------------------------
__global__ __launch_bounds__(256) void absmax_k(const float* __restrict__ W1,
                                                const float* __restrict__ W2,
                                                const float* __restrict__ Wr,
                                                const float* __restrict__ W3,
                                                unsigned* __restrict__ smax) {
  const int tens = blockIdx.x >> 6;   // 0..3
  const int sub  = blockIdx.x & 63;
  const float* W; int n4;
  switch (tens) {
    case 0:  W = W1; n4 = (H1_ * NIN_) >> 2; break;
    case 1:  W = W2; n4 = (H2_ * H1_) >> 2;  break;
    case 2:  W = Wr; n4 = (H2_ * H2_) >> 2;  break;
    default: W = W3; n4 = (OUT_ * H2_) >> 2; break;
  }
  const int per = n4 >> 6;            // 1024 (W1/W2/Wr) or 256 (W3)
  const float4* W4 = (const float4*)W + sub * per;
  int tid = threadIdx.x;
  float m = 0.f;
  for (int i = tid; i < per; i += 256) {
    float4 v = W4[i];
    m = fmaxf(m, fmaxf(fmaxf(fabsf(v.x), fabsf(v.y)), fmaxf(fabsf(v.z), fabsf(v.w))));
  }
  __shared__ float red[256];
  red[tid] = m;
  __syncthreads();
  for (int s = 128; s > 0; s >>= 1) {
    if (tid < s) red[tid] = fmaxf(red[tid], red[tid + s]);
    __syncthreads();
  }
  if (tid == 0) atomicMax(smax + tens, __float_as_uint(red[0]));
}

// ---------------------------------------------------------------------------
// Fused quantization of all four weight tensors (one launch).
//  blocks 0..1023    : W1 -> fp32 q*s, transposed [NIN][H1]    (W1qT)
//  blocks 1024..2047 : W2 -> int8 q, row-major [H2][H1]        (W2i8)
//  blocks 2048..3071 : Wr -> int8 q, presyn-major [H2][H2]     (WrT, transposed)
//  blocks 3072..3327 : W3 -> int8 q, row-major [OUT][H2]       (W3i8)
// ---------------------------------------------------------------------------
__global__ void quant_all_k(const float* __restrict__ W1, const float* __restrict__ W2,
                            const float* __restrict__ Wr, const float* __restrict__ W3,
                            const unsigned* __restrict__ smax,
                            float* __restrict__ scales,
                            float* __restrict__ W1qT, signed char* __restrict__ W2i8,
                            signed char* __restrict__ WrT, signed char* __restrict__ W3i8) {
  const int blk = blockIdx.x;
  if (blk == 0 && threadIdx.x < 4)
    scales[threadIdx.x] = __uint_as_float(smax[threadIdx.x]) / 127.0f;
  if (blk < 1024) {
    int idx = blk * 256 + threadIdx.x;
    int h = idx & (H1_ - 1), i = idx >> 9;
    float s = __uint_as_float(smax[0]) / 127.0f;
    float q = rintf(W1[h * NIN_ + i] / s);
    q = fminf(fmaxf(q, -127.f), 127.f);
    W1qT[idx] = q * s;
  } else if (blk < 2048) {
    int idx = (blk - 1024) * 256 + threadIdx.x;
    float s = __uint_as_float(smax[1]) / 127.0f;
    float q = rintf(W2[idx] / s);
    q = fminf(fmaxf(q, -127.f), 127.f);
    W2i8[idx] = (signed char)q;
  } else if (blk < 3072) {
    int idx = (blk - 2048) * 256 + threadIdx.x;
    int r = idx >> 9, c = idx & (H2_ - 1);
    float s = __uint_as_float(smax[2]) / 127.0f;
    float q = rintf(Wr[idx] / s);
    q = fminf(fmaxf(q, -127.f), 127.f);
    WrT[(size_t)c * H2_ + r] = (signed char)q;
  } else {
    int idx = (blk - 3072) * 256 + threadIdx.x;
    float s = __uint_as_float(smax[3]) / 127.0f;
    float q = rintf(W3[idx] / s);
    q = fminf(fmaxf(q, -127.f), 127.f);
    W3i8[idx] = (signed char)q;
  }
}

// ---------------------------------------------------------------------------
// Phase A: cur1[t,b,h] = sum_i data[b,i,t] * W1qT[i,h].  fp32.
// ROUND-2 VERIFIED STRUCTURE, PARKED at ~390 us (56% fp32 peak).
// FMA order: per output element a single accumulator over k ascending
// 0..511 -> bit-identical cur1.  GOLDEN arithmetic preserved.
// ---------------------------------------------------------------------------
__global__ __launch_bounds__(512, 6) void gemm_cur1_k(const float* __restrict__ data,
                                                      const float* __restrict__ W1qT,
                                                      float* __restrict__ cur1) {
  const int b  = blockIdx.y;
  const int t0 = (blockIdx.x >> 2) << 7;
  const int h0 = (blockIdx.x & 3) << 7;
  const int tid = threadIdx.x;

  __shared__ float As[2][16][128];   // 16 KB
  __shared__ float Bs[2][16][128];   // 16 KB

  const int ty = tid >> 4, tx = tid & 15;   // ty 0..31, tx 0..15
  const int wv = tid >> 6;                  // 0..7
  const int ln = tid & 63;

  float acc[4][8];
#pragma unroll
  for (int i = 0; i < 4; i++)
#pragma unroll
    for (int j = 0; j < 8; j++) acc[i][j] = 0.f;

  const float* dbase = data + (size_t)b * NIN_ * T_;

  auto issue = [&](int kb, int buf) {
    const int kr = (wv << 1) + (ln >> 5);
    const float* ga = dbase + (size_t)(kb + kr) * T_ + t0 + ((ln & 31) << 2);
    __builtin_amdgcn_global_load_lds((gl_cu)ga, (ls_u)&As[buf][wv << 1][0], 16, 0, 0);
    const float* gb = W1qT + (size_t)(kb + kr) * H1_ + h0 + ((ln & 31) << 2);
    __builtin_amdgcn_global_load_lds((gl_cu)gb, (ls_u)&Bs[buf][wv << 1][0], 16, 0, 0);
  };

  issue(0, 0);

  for (int p = 0; p < 32; p++) {
    const int cur = p & 1;
    __syncthreads();
    if (p < 31) issue((p + 1) << 4, cur ^ 1);
#pragma unroll
    for (int k = 0; k < 16; k++) {
      float4 A0 = *(const float4*)&As[cur][k][ty * 4];
      float4 B0 = *(const float4*)&Bs[cur][k][tx * 4];
      float4 B1 = *(const float4*)&Bs[cur][k][64 + tx * 4];
      float a[4] = {A0.x, A0.y, A0.z, A0.w};
      float w[8] = {B0.x, B0.y, B0.z, B0.w, B1.x, B1.y, B1.z, B1.w};
#pragma unroll
      for (int i = 0; i < 4; i++)
#pragma unroll
        for (int j = 0; j < 8; j++)
          acc[i][j] = fmaf(a[i], w[j], acc[i][j]);
    }
  }

#pragma unroll
  for (int i = 0; i < 4; i++) {
    int row = ty * 4 + i;
    float* op = cur1 + (size_t)(t0 + row) * (B_ * H1_) + (size_t)b * H1_ + h0;
    float4 cA = {acc[i][0], acc[i][1], acc[i][2], acc[i][3]};
    float4 cB = {acc[i][4], acc[i][5], acc[i][6], acc[i][7]};
    *(float4*)(op + tx * 4)      = cA;
    *(float4*)(op + 64 + tx * 4) = cB;
  }
}

// ---------------------------------------------------------------------------
// scan1: parallel per-neuron layer-1 LIF scan (op order unchanged), unroll 8.
// ---------------------------------------------------------------------------
__global__ __launch_bounds__(256) void scan1_k(const float* __restrict__ cur1,
                                               unsigned char* __restrict__ s1u,
                                               const float* __restrict__ beta1p,
                                               const float* __restrict__ th1p) {
  const int n = blockIdx.x * 256 + threadIdx.x;
  const float b1 = fminf(fmaxf(beta1p[0], 0.f), 1.f);
  const float th1 = th1p[0];
  const size_t S = (size_t)B_ * H1_;
  float m1 = 0.f;
  for (int t = 0; t < T_; t += 8) {
    float c[8];
#pragma unroll
    for (int j = 0; j < 8; j++) c[j] = cur1[(size_t)(t + j) * S + n];
#pragma unroll
    for (int j = 0; j < 8; j++) {
      m1 = b1 * m1 + c[j];
      bool s = m1 - th1 > 0.f;
      if (s) m1 = 0.f;
      s1u[(size_t)(t + j) * S + n] = s;
    }
  }
}

// ---------------------------------------------------------------------------
// Spike GEMM via i8 MFMA (exact integer sums, i32 accumulate).  VERIFIED.
// Double-buffered LDS, one barrier per K-block; m-tile on blockIdx.x.
// ---------------------------------------------------------------------------
__global__ __launch_bounds__(256) void gemm_spk_k(const unsigned char* __restrict__ A8,
                                                  const signed char* __restrict__ Bw,
                                                  float* __restrict__ C, int N) {
  __shared__ __align__(16) signed char As[2][128 * 80];   // 20 KB
  __shared__ __align__(16) signed char Bs[2][128 * 80];   // 20 KB
  const int tid = threadIdx.x;
  const int m0 = blockIdx.x << 7;
  const int n0 = blockIdx.y << 7;
  const int lane = tid & 63, wave = tid >> 6;
  const int quad = lane >> 4, lm = lane & 15;
  const int wm = wave << 5;

  i32x4 acc[2][8];
#pragma unroll
  for (int s = 0; s < 2; s++)
#pragma unroll
    for (int n = 0; n < 8; n++) acc[s][n] = (i32x4){0, 0, 0, 0};

  const int row = tid >> 2;            // 0..63 (+64 on second pass)
  const int offB = (tid & 3) << 4;     // 0/16/32/48 within 64-byte k-window

  uint4 av[2], bv[2];
  auto gload = [&](int kb) {
#pragma unroll
    for (int i = 0; i < 2; i++) {
      const int r = row + (i << 6);
      av[i] = *(const uint4*)(A8 + (size_t)(m0 + r) * 512 + kb + offB);
      bv[i] = *(const uint4*)(Bw + (size_t)(n0 + r) * 512 + kb + offB);
    }
  };

  gload(0);
  int buf = 0;
  for (int kb8 = 0; kb8 < 8; kb8++) {
#pragma unroll
    for (int i = 0; i < 2; i++) {
      const int r = row + (i << 6);
      *(uint4*)&As[buf][r * 80 + offB] = av[i];
      *(uint4*)&Bs[buf][r * 80 + offB] = bv[i];
    }
    __syncthreads();
    if (kb8 < 7) gload((kb8 + 1) << 6);   // overlaps with MFMAs below
    i32x4 a0 = *(const i32x4*)&As[buf][(wm + lm) * 80 + (quad << 4)];
    i32x4 a1 = *(const i32x4*)&As[buf][(wm + 16 + lm) * 80 + (quad << 4)];
    i32x4 bq[8];
#pragma unroll
    for (int n = 0; n < 8; n++)
      bq[n] = *(const i32x4*)&Bs[buf][((n << 4) + lm) * 80 + (quad << 4)];
#pragma unroll
    for (int n = 0; n < 8; n++) {
      acc[0][n] = __builtin_amdgcn_mfma_i32_16x16x64_i8(a0, bq[n], acc[0][n], 0, 0, 0);
      acc[1][n] = __builtin_amdgcn_mfma_i32_16x16x64_i8(a1, bq[n], acc[1][n], 0, 0, 0);
    }
    buf ^= 1;
  }

#pragma unroll
  for (int s = 0; s < 2; s++)
#pragma unroll
    for (int n = 0; n < 8; n++) {
      int orow = m0 + wm + (s << 4) + quad * 4;
      int col = n0 + (n << 4) + lm;
#pragma unroll
      for (int r = 0; r < 4; r++)
        C[(size_t)(orow + r) * N + col] = (float)acc[s][n][r];
    }
}

// ---------------------------------------------------------------------------
__device__ __forceinline__ void unp_add(unsigned w, int* a) {
  int iw = (int)w;
  a[0] += (iw << 24) >> 24;
  a[1] += (iw << 16) >> 24;
  a[2] += (iw << 8) >> 24;
  a[3] += iw >> 24;
}

// Raw barrier: LDS ordering only (lgkmcnt), no vmcnt drain -- lets the
// cur2a prefetch and sru stores stay in flight across step boundaries.
// sched_barrier(0) per rule #18 (no hoisting past the inline-asm waitcnt).
__device__ __forceinline__ void lds_barrier() {
  asm volatile("s_waitcnt lgkmcnt(0)" ::: "memory");
  __builtin_amdgcn_s_barrier();
  __builtin_amdgcn_sched_barrier(0);
}

// ---------------------------------------------------------------------------
// Sequential recurrent layer.  One block per batch row, 1024 threads.
// Round-8: (a) cur2a software-pipelined ONE FULL STEP ahead (load for t+1
// issued at top of step t, consumed after S1 of step t+1 -> ~full-step
// latency cover); (b) both per-step barriers are lgkm-only raw barriers --
// __syncthreads' forced vmcnt(0) drain killed the prefetch 512 times.
// Hazard audit: all cross-step LDS hazards (red rewrite, lst/nc build->read)
// are ordered by lgkmcnt(0)+s_barrier; the only VMEM crossing barriers is
// cur2a (read-only in-kernel) and sru stores (never read in-kernel).
// Arithmetic identical -> bit-identical sru.
// ---------------------------------------------------------------------------
__global__ __launch_bounds__(1024) void recurrent_k(
    const float* __restrict__ cur2a,       // [T*B, H2]
    const signed char* __restrict__ WrT,   // [H2][H2] presyn-major
    unsigned char* __restrict__ sru,       // [T*B, H2]
    const float* __restrict__ scales,
    const float* __restrict__ betarp, const float* __restrict__ thrp) {
  const int b = blockIdx.x;
  const int tid = threadIdx.x;
  const float s2sc = scales[1];
  const float srsc = scales[2];
  const float br = fminf(fmaxf(betarp[0], 0.f), 1.f);
  const float thr = thrp[0];

  const unsigned* WrT4 = (const unsigned*)WrT;   // [H2][128] dwords

  __shared__ unsigned WrL[256 * 128];   // 128 KB: presyn rows 0..255
  __shared__ int red[8][H2_];           // 16 KB
  __shared__ int lstLo[2][256];         // 2 KB
  __shared__ int lstHi[2][256];         // 2 KB
  __shared__ int ncLo[2], ncHi[2];

  {
    const uint4* src = (const uint4*)WrT4;
    uint4* dst = (uint4*)WrL;
    for (int i = tid; i < 8192; i += 1024) dst[i] = src[i];
  }
  if (tid < 2) { ncLo[tid] = 0; ncHi[tid] = 0; }
  __syncthreads();

  float mr = 0.f, sr_own = 0.f;
  const int g = tid >> 7;        // 0..7
  const int c = tid & 127;       // dword column

  float c2 = 0.f;
  if (tid < H2_) c2 = cur2a[(size_t)b * H2_ + tid];          // t = 0

  for (int t = 0; t < T_; t++) {
    const int old = t & 1, nxt = old ^ 1;
    float c2n = 0.f;
    if (t + 1 < T_ && tid < H2_)
      c2n = cur2a[((size_t)(t + 1) * B_ + b) * H2_ + tid];   // prefetch t+1
    if (tid == 1022) ncLo[nxt] = 0;
    if (tid == 1023) ncHi[nxt] = 0;
    const int nLo = ncLo[old];
    const int nHi = ncHi[old];
    const int* LLo = lstLo[old];
    const int* LHi = lstHi[old];

    int a4[4] = {0, 0, 0, 0};
    // ---- LDS-resident half (rows < 256) ----
    {
      int k = g;
      for (; k + 56 < nLo; k += 64) {
        int i0 = LLo[k],      i1 = LLo[k + 8],  i2 = LLo[k + 16], i3 = LLo[k + 24];
        int i4 = LLo[k + 32], i5 = LLo[k + 40], i6 = LLo[k + 48], i7 = LLo[k + 56];
        unsigned w0 = WrL[(i0 << 7) + c], w1 = WrL[(i1 << 7) + c];
        unsigned w2 = WrL[(i2 << 7) + c], w3 = WrL[(i3 << 7) + c];
        unsigned w4 = WrL[(i4 << 7) + c], w5 = WrL[(i5 << 7) + c];
        unsigned w6 = WrL[(i6 << 7) + c], w7 = WrL[(i7 << 7) + c];
        unp_add(w0, a4); unp_add(w1, a4); unp_add(w2, a4); unp_add(w3, a4);
        unp_add(w4, a4); unp_add(w5, a4); unp_add(w6, a4); unp_add(w7, a4);
      }
      for (; k + 24 < nLo; k += 32) {
        int i0 = LLo[k], i1 = LLo[k + 8], i2 = LLo[k + 16], i3 = LLo[k + 24];
        unsigned w0 = WrL[(i0 << 7) + c], w1 = WrL[(i1 << 7) + c];
        unsigned w2 = WrL[(i2 << 7) + c], w3 = WrL[(i3 << 7) + c];
        unp_add(w0, a4); unp_add(w1, a4); unp_add(w2, a4); unp_add(w3, a4);
      }
      for (; k < nLo; k += 8) unp_add(WrL[(LLo[k] << 7) + c], a4);
    }
    // ---- global half (rows >= 256) ----
    {
      int k = g;
      for (; k + 56 < nHi; k += 64) {
        int i0 = LHi[k],      i1 = LHi[k + 8],  i2 = LHi[k + 16], i3 = LHi[k + 24];
        int i4 = LHi[k + 32], i5 = LHi[k + 40], i6 = LHi[k + 48], i7 = LHi[k + 56];
        unsigned w0 = WrT4[(i0 << 7) + c], w1 = WrT4[(i1 << 7) + c];
        unsigned w2 = WrT4[(i2 << 7) + c], w3 = WrT4[(i3 << 7) + c];
        unsigned w4 = WrT4[(i4 << 7) + c], w5 = WrT4[(i5 << 7) + c];
        unsigned w6 = WrT4[(i6 << 7) + c], w7 = WrT4[(i7 << 7) + c];
        unp_add(w0, a4); unp_add(w1, a4); unp_add(w2, a4); unp_add(w3, a4);
        unp_add(w4, a4); unp_add(w5, a4); unp_add(w6, a4); unp_add(w7, a4);
      }
      for (; k + 24 < nHi; k += 32) {
        int i0 = LHi[k], i1 = LHi[k + 8], i2 = LHi[k + 16], i3 = LHi[k + 24];
        unsigned w0 = WrT4[(i0 << 7) + c], w1 = WrT4[(i1 << 7) + c];
        unsigned w2 = WrT4[(i2 << 7) + c], w3 = WrT4[(i3 << 7) + c];
        unp_add(w0, a4); unp_add(w1, a4); unp_add(w2, a4); unp_add(w3, a4);
      }
      for (; k < nHi; k += 8) unp_add(WrT4[(LHi[k] << 7) + c], a4);
    }
    *(int4*)&red[g][c << 2] = make_int4(a4[0], a4[1], a4[2], a4[3]);
    lds_barrier();                                 // S1 (lgkm-only)

    bool spike = false;
    if (tid < H2_) {
      int acc = red[0][tid] + red[1][tid] + red[2][tid] + red[3][tid]
              + red[4][tid] + red[5][tid] + red[6][tid] + red[7][tid];
      float h = s2sc * c2 + srsc * (float)acc;
      mr = (br * mr + h) * (1.f - sr_own);
      sr_own = (mr - thr > 0.f) ? 1.f : 0.f;
      sru[((size_t)t * B_ + b) * H2_ + tid] = (unsigned char)(sr_own != 0.f);
      spike = (sr_own != 0.f);
    }
    unsigned long long bm = __ballot(spike);
    if (bm != 0ull) {
      const int lane = tid & 63;
      const int ldr = (int)__ffsll((long long)bm) - 1;
      int* cnt = (tid < 256) ? &ncLo[nxt] : &ncHi[nxt];   // wave-uniform choice
      int* dst = (tid < 256) ? lstLo[nxt] : lstHi[nxt];
      int base = 0;
      if (lane == ldr) base = atomicAdd(cnt, (int)__popcll(bm));
      base = __shfl(base, ldr);
      if (spike)
        dst[base + (int)__popcll(bm & ((1ull << lane) - 1ull))] = tid;
    }
    lds_barrier();                                 // S2 (lgkm-only)
    c2 = c2n;
  }
}

// ---------------------------------------------------------------------------
// scan3: parallel layer-2 LIF scan (op order unchanged), unroll 8.
// ---------------------------------------------------------------------------
__global__ __launch_bounds__(256) void scan3_k(const float* __restrict__ cur3,
                                               float* __restrict__ out,
                                               const float* __restrict__ scales,
                                               const float* __restrict__ beta2p,
                                               const float* __restrict__ th2p) {
  const int n = blockIdx.x * 256 + threadIdx.x;
  const float s3sc = scales[3];
  const float b2 = fminf(fmaxf(beta2p[0], 0.f), 1.f);
  const float th2 = th2p[0];
  const size_t S = (size_t)B_ * OUT_;
  float m2 = 0.f;
  for (int t = 0; t < T_; t += 8) {
    float v[8];
#pragma unroll
    for (int j = 0; j < 8; j++) v[j] = cur3[(size_t)(t + j) * S + n];
#pragma unroll
    for (int j = 0; j < 8; j++) {
      m2 = b2 * m2 + s3sc * v[j];
      float p = (m2 - th2 > 0.f) ? 1.f : 0.f;
      m2 *= (1.f - p);
      out[(size_t)(t + j) * S + n] = p;
    }
  }
}

// ---------------------------------------------------------------------------
extern "C" void kernel_launch(void* const* d_in, const int* in_sizes, int n_in,
                              void* d_out, int out_size, void* d_ws, size_t ws_size,
                              hipStream_t stream) {
  const float* data  = (const float*)d_in[0];
  const float* W1    = (const float*)d_in[1];
  const float* W2    = (const float*)d_in[2];
  const float* Wr    = (const float*)d_in[3];
  const float* W3    = (const float*)d_in[4];
  const float* beta1 = (const float*)d_in[5];
  const float* th1   = (const float*)d_in[6];
  const float* betar = (const float*)d_in[7];
  const float* thr   = (const float*)d_in[8];
  const float* beta2 = (const float*)d_in[9];
  const float* th2   = (const float*)d_in[10];

  char* ws = (char*)d_ws;
  float*         scales = (float*)ws;                                   // @0 (16 B)
  unsigned*      smax   = (unsigned*)(ws + 64);                         // @64 (16 B)
  float*         W1qT   = (float*)(ws + 4096);                          // 1 MB [NIN][H1]
  signed char*   W2i8   = (signed char*)(ws + 4096 + 1048576);          // 256 KB [H2][H1]
  signed char*   W3i8   = (signed char*)(ws + 4096 + 1048576 + 524288); // 64 KB [OUT][H2]
  signed char*   WrT    = (signed char*)(ws + 4096 + 1048576 + 524288 + 131072); // 256 KB
  // region A (128 MB): cur1 -> cur2a -> cur3 (sequential lifetimes)
  float*         regA   = (float*)(ws + (size_t)4194304);
  // region B (64 MB): s1u + sru
  unsigned char* regB   = (unsigned char*)(ws + (size_t)4194304 + 134217728);

  float* cur1  = regA;
  float* cur2a = regA;
  float* cur3  = regA;
  unsigned char* s1u = regB;
  unsigned char* sru = regB + (size_t)33554432;

  hipMemsetAsync(smax, 0, 16, stream);
  hipLaunchKernelGGL(absmax_k, dim3(256), dim3(256), 0, stream, W1, W2, Wr, W3, smax);
  hipLaunchKernelGGL(quant_all_k, dim3(3328), dim3(256), 0, stream,
                     W1, W2, Wr, W3, smax, scales, W1qT, W2i8, WrT, W3i8);

  hipLaunchKernelGGL(gemm_cur1_k, dim3(8, 256), dim3(512), 0, stream, data, W1qT, cur1);
  hipLaunchKernelGGL(scan1_k, dim3((B_ * H1_) / 256), dim3(256), 0, stream, cur1, s1u, beta1, th1);
  hipLaunchKernelGGL(gemm_spk_k, dim3(512, 4), dim3(256), 0, stream, s1u, W2i8, cur2a, H2_);
  hipLaunchKernelGGL(recurrent_k, dim3(256), dim3(1024), 0, stream, cur2a, WrT, sru, scales, betar, thr);
  hipLaunchKernelGGL(gemm_spk_k, dim3(512, 1), dim3(256), 0, stream, sru, W3i8, cur3, OUT_);
  hipLaunchKernelGGL(scan3_k, dim3((B_ * OUT_) / 256), dim3(256), 0, stream, cur3, (float*)d_out, scales, beta2, th2);
}

// Round 9
// 1003.935 us; speedup vs baseline: 1.0018x; 1.0018x over previous
//
#include <hip/hip_runtime.h>

#define B_   256
#define NIN_ 512
#define T_   256
#define H1_  512
#define H2_  512
#define OUT_ 128

typedef __attribute__((ext_vector_type(4))) int i32x4;
typedef __attribute__((address_space(1))) const unsigned int* gl_cu;
typedef __attribute__((address_space(3))) unsigned int* ls_u;

// ---------------------------------------------------------------------------
// Per-tensor absmax, parallel: 64 blocks per tensor, atomicMax on uint bits
// (valid: all values are fabs() >= 0; IEEE non-negative floats order as uints).
// smax[] zeroed by hipMemsetAsync.  Max is order-independent -> same scale.
// ---------------------------------------------------------------------------
__global__ __launch_bounds__(256) void absmax_k(const float* __restrict__ W1,
                                                const float* __restrict__ W2,
                                                const float* __restrict__ Wr,
                                                const float* __restrict__ W3,
                                                unsigned* __restrict__ smax) {
  const int tens = blockIdx.x >> 6;   // 0..3
  const int sub  = blockIdx.x & 63;
  const float* W; int n4;
  switch (tens) {
    case 0:  W = W1; n4 = (H1_ * NIN_) >> 2; break;
    case 1:  W = W2; n4 = (H2_ * H1_) >> 2;  break;
    case 2:  W = Wr; n4 = (H2_ * H2_) >> 2;  break;
    default: W = W3; n4 = (OUT_ * H2_) >> 2; break;
  }
  const int per = n4 >> 6;            // 1024 (W1/W2/Wr) or 256 (W3)
  const float4* W4 = (const float4*)W + sub * per;
  int tid = threadIdx.x;
  float m = 0.f;
  for (int i = tid; i < per; i += 256) {
    float4 v = W4[i];
    m = fmaxf(m, fmaxf(fmaxf(fabsf(v.x), fabsf(v.y)), fmaxf(fabsf(v.z), fabsf(v.w))));
  }
  __shared__ float red[256];
  red[tid] = m;
  __syncthreads();
  for (int s = 128; s > 0; s >>= 1) {
    if (tid < s) red[tid] = fmaxf(red[tid], red[tid + s]);
    __syncthreads();
  }
  if (tid == 0) atomicMax(smax + tens, __float_as_uint(red[0]));
}

// ---------------------------------------------------------------------------
// Fused quantization of all four weight tensors (one launch).
//  blocks 0..1023    : W1 -> fp32 q*s, transposed [NIN][H1]    (W1qT)
//  blocks 1024..2047 : W2 -> int8 q, row-major [H2][H1]        (W2i8)
//  blocks 2048..3071 : Wr -> int8 q, presyn-major [H2][H2]     (WrT, transposed)
//  blocks 3072..3327 : W3 -> int8 q, row-major [OUT][H2]       (W3i8)
// ---------------------------------------------------------------------------
__global__ void quant_all_k(const float* __restrict__ W1, const float* __restrict__ W2,
                            const float* __restrict__ Wr, const float* __restrict__ W3,
                            const unsigned* __restrict__ smax,
                            float* __restrict__ scales,
                            float* __restrict__ W1qT, signed char* __restrict__ W2i8,
                            signed char* __restrict__ WrT, signed char* __restrict__ W3i8) {
  const int blk = blockIdx.x;
  if (blk == 0 && threadIdx.x < 4)
    scales[threadIdx.x] = __uint_as_float(smax[threadIdx.x]) / 127.0f;
  if (blk < 1024) {
    int idx = blk * 256 + threadIdx.x;
    int h = idx & (H1_ - 1), i = idx >> 9;
    float s = __uint_as_float(smax[0]) / 127.0f;
    float q = rintf(W1[h * NIN_ + i] / s);
    q = fminf(fmaxf(q, -127.f), 127.f);
    W1qT[idx] = q * s;
  } else if (blk < 2048) {
    int idx = (blk - 1024) * 256 + threadIdx.x;
    float s = __uint_as_float(smax[1]) / 127.0f;
    float q = rintf(W2[idx] / s);
    q = fminf(fmaxf(q, -127.f), 127.f);
    W2i8[idx] = (signed char)q;
  } else if (blk < 3072) {
    int idx = (blk - 2048) * 256 + threadIdx.x;
    int r = idx >> 9, c = idx & (H2_ - 1);
    float s = __uint_as_float(smax[2]) / 127.0f;
    float q = rintf(Wr[idx] / s);
    q = fminf(fmaxf(q, -127.f), 127.f);
    WrT[(size_t)c * H2_ + r] = (signed char)q;
  } else {
    int idx = (blk - 3072) * 256 + threadIdx.x;
    float s = __uint_as_float(smax[3]) / 127.0f;
    float q = rintf(W3[idx] / s);
    q = fminf(fmaxf(q, -127.f), 127.f);
    W3i8[idx] = (signed char)q;
  }
}

// ---------------------------------------------------------------------------
// Phase A: cur1[t,b,h] = sum_i data[b,i,t] * W1qT[i,h].  fp32.
// ROUND-2 VERIFIED STRUCTURE, PARKED at ~390 us (56% fp32 peak).
// FMA order: per output element a single accumulator over k ascending
// 0..511 -> bit-identical cur1.  GOLDEN arithmetic preserved.
// ---------------------------------------------------------------------------
__global__ __launch_bounds__(512, 6) void gemm_cur1_k(const float* __restrict__ data,
                                                      const float* __restrict__ W1qT,
                                                      float* __restrict__ cur1) {
  const int b  = blockIdx.y;
  const int t0 = (blockIdx.x >> 2) << 7;
  const int h0 = (blockIdx.x & 3) << 7;
  const int tid = threadIdx.x;

  __shared__ float As[2][16][128];   // 16 KB
  __shared__ float Bs[2][16][128];   // 16 KB

  const int ty = tid >> 4, tx = tid & 15;   // ty 0..31, tx 0..15
  const int wv = tid >> 6;                  // 0..7
  const int ln = tid & 63;

  float acc[4][8];
#pragma unroll
  for (int i = 0; i < 4; i++)
#pragma unroll
    for (int j = 0; j < 8; j++) acc[i][j] = 0.f;

  const float* dbase = data + (size_t)b * NIN_ * T_;

  auto issue = [&](int kb, int buf) {
    const int kr = (wv << 1) + (ln >> 5);
    const float* ga = dbase + (size_t)(kb + kr) * T_ + t0 + ((ln & 31) << 2);
    __builtin_amdgcn_global_load_lds((gl_cu)ga, (ls_u)&As[buf][wv << 1][0], 16, 0, 0);
    const float* gb = W1qT + (size_t)(kb + kr) * H1_ + h0 + ((ln & 31) << 2);
    __builtin_amdgcn_global_load_lds((gl_cu)gb, (ls_u)&Bs[buf][wv << 1][0], 16, 0, 0);
  };

  issue(0, 0);

  for (int p = 0; p < 32; p++) {
    const int cur = p & 1;
    __syncthreads();
    if (p < 31) issue((p + 1) << 4, cur ^ 1);
#pragma unroll
    for (int k = 0; k < 16; k++) {
      float4 A0 = *(const float4*)&As[cur][k][ty * 4];
      float4 B0 = *(const float4*)&Bs[cur][k][tx * 4];
      float4 B1 = *(const float4*)&Bs[cur][k][64 + tx * 4];
      float a[4] = {A0.x, A0.y, A0.z, A0.w};
      float w[8] = {B0.x, B0.y, B0.z, B0.w, B1.x, B1.y, B1.z, B1.w};
#pragma unroll
      for (int i = 0; i < 4; i++)
#pragma unroll
        for (int j = 0; j < 8; j++)
          acc[i][j] = fmaf(a[i], w[j], acc[i][j]);
    }
  }

#pragma unroll
  for (int i = 0; i < 4; i++) {
    int row = ty * 4 + i;
    float* op = cur1 + (size_t)(t0 + row) * (B_ * H1_) + (size_t)b * H1_ + h0;
    float4 cA = {acc[i][0], acc[i][1], acc[i][2], acc[i][3]};
    float4 cB = {acc[i][4], acc[i][5], acc[i][6], acc[i][7]};
    *(float4*)(op + tx * 4)      = cA;
    *(float4*)(op + 64 + tx * 4) = cB;
  }
}

// ---------------------------------------------------------------------------
// scan1: parallel per-neuron layer-1 LIF scan (op order unchanged), unroll 8.
// ---------------------------------------------------------------------------
__global__ __launch_bounds__(256) void scan1_k(const float* __restrict__ cur1,
                                               unsigned char* __restrict__ s1u,
                                               const float* __restrict__ beta1p,
                                               const float* __restrict__ th1p) {
  const int n = blockIdx.x * 256 + threadIdx.x;
  const float b1 = fminf(fmaxf(beta1p[0], 0.f), 1.f);
  const float th1 = th1p[0];
  const size_t S = (size_t)B_ * H1_;
  float m1 = 0.f;
  for (int t = 0; t < T_; t += 8) {
    float c[8];
#pragma unroll
    for (int j = 0; j < 8; j++) c[j] = cur1[(size_t)(t + j) * S + n];
#pragma unroll
    for (int j = 0; j < 8; j++) {
      m1 = b1 * m1 + c[j];
      bool s = m1 - th1 > 0.f;
      if (s) m1 = 0.f;
      s1u[(size_t)(t + j) * S + n] = s;
    }
  }
}

// ---------------------------------------------------------------------------
// Spike GEMM via i8 MFMA (exact integer sums, i32 accumulate).  VERIFIED.
// Double-buffered LDS, one barrier per K-block; m-tile on blockIdx.x.
// ---------------------------------------------------------------------------
__global__ __launch_bounds__(256) void gemm_spk_k(const unsigned char* __restrict__ A8,
                                                  const signed char* __restrict__ Bw,
                                                  float* __restrict__ C, int N) {
  __shared__ __align__(16) signed char As[2][128 * 80];   // 20 KB
  __shared__ __align__(16) signed char Bs[2][128 * 80];   // 20 KB
  const int tid = threadIdx.x;
  const int m0 = blockIdx.x << 7;
  const int n0 = blockIdx.y << 7;
  const int lane = tid & 63, wave = tid >> 6;
  const int quad = lane >> 4, lm = lane & 15;
  const int wm = wave << 5;

  i32x4 acc[2][8];
#pragma unroll
  for (int s = 0; s < 2; s++)
#pragma unroll
    for (int n = 0; n < 8; n++) acc[s][n] = (i32x4){0, 0, 0, 0};

  const int row = tid >> 2;            // 0..63 (+64 on second pass)
  const int offB = (tid & 3) << 4;     // 0/16/32/48 within 64-byte k-window

  uint4 av[2], bv[2];
  auto gload = [&](int kb) {
#pragma unroll
    for (int i = 0; i < 2; i++) {
      const int r = row + (i << 6);
      av[i] = *(const uint4*)(A8 + (size_t)(m0 + r) * 512 + kb + offB);
      bv[i] = *(const uint4*)(Bw + (size_t)(n0 + r) * 512 + kb + offB);
    }
  };

  gload(0);
  int buf = 0;
  for (int kb8 = 0; kb8 < 8; kb8++) {
#pragma unroll
    for (int i = 0; i < 2; i++) {
      const int r = row + (i << 6);
      *(uint4*)&As[buf][r * 80 + offB] = av[i];
      *(uint4*)&Bs[buf][r * 80 + offB] = bv[i];
    }
    __syncthreads();
    if (kb8 < 7) gload((kb8 + 1) << 6);   // overlaps with MFMAs below
    i32x4 a0 = *(const i32x4*)&As[buf][(wm + lm) * 80 + (quad << 4)];
    i32x4 a1 = *(const i32x4*)&As[buf][(wm + 16 + lm) * 80 + (quad << 4)];
    i32x4 bq[8];
#pragma unroll
    for (int n = 0; n < 8; n++)
      bq[n] = *(const i32x4*)&Bs[buf][((n << 4) + lm) * 80 + (quad << 4)];
#pragma unroll
    for (int n = 0; n < 8; n++) {
      acc[0][n] = __builtin_amdgcn_mfma_i32_16x16x64_i8(a0, bq[n], acc[0][n], 0, 0, 0);
      acc[1][n] = __builtin_amdgcn_mfma_i32_16x16x64_i8(a1, bq[n], acc[1][n], 0, 0, 0);
    }
    buf ^= 1;
  }

#pragma unroll
  for (int s = 0; s < 2; s++)
#pragma unroll
    for (int n = 0; n < 8; n++) {
      int orow = m0 + wm + (s << 4) + quad * 4;
      int col = n0 + (n << 4) + lm;
#pragma unroll
      for (int r = 0; r < 4; r++)
        C[(size_t)(orow + r) * N + col] = (float)acc[s][n][r];
    }
}

// ---------------------------------------------------------------------------
__device__ __forceinline__ void unp_add(unsigned w, int* a) {
  int iw = (int)w;
  a[0] += (iw << 24) >> 24;
  a[1] += (iw << 16) >> 24;
  a[2] += (iw << 8) >> 24;
  a[3] += iw >> 24;
}

// ---------------------------------------------------------------------------
// Sequential recurrent layer.  One block per batch row.
// Round-9: 512 threads (8 waves) instead of 1024 (16 waves).  Per-step
// compute is tiny (~100 spikes x 4 adds); the step cost is the two
// 16-wave barriers + the 8-partial reduce.  Halving waves halves barrier
// sync/straggler cost; reduce reads 4 partials instead of 8.  Gather work
// per group doubles but remains trivial.  Barriers back to __syncthreads
// (round-8's lgkm-only + prefetch variant regressed).  Spike partition
// over 4 groups -- integer partials, order-independent -> bit-identical sru.
// ---------------------------------------------------------------------------
__global__ __launch_bounds__(512) void recurrent_k(
    const float* __restrict__ cur2a,       // [T*B, H2]
    const signed char* __restrict__ WrT,   // [H2][H2] presyn-major
    unsigned char* __restrict__ sru,       // [T*B, H2]
    const float* __restrict__ scales,
    const float* __restrict__ betarp, const float* __restrict__ thrp) {
  const int b = blockIdx.x;
  const int tid = threadIdx.x;           // 0..511 == neuron id
  const float s2sc = scales[1];
  const float srsc = scales[2];
  const float br = fminf(fmaxf(betarp[0], 0.f), 1.f);
  const float thr = thrp[0];

  const unsigned* WrT4 = (const unsigned*)WrT;   // [H2][128] dwords

  __shared__ unsigned WrL[256 * 128];   // 128 KB: presyn rows 0..255
  __shared__ int red[4][H2_];           // 8 KB
  __shared__ int lstLo[2][256];         // 2 KB
  __shared__ int lstHi[2][256];         // 2 KB
  __shared__ int ncLo[2], ncHi[2];

  {
    const uint4* src = (const uint4*)WrT4;
    uint4* dst = (uint4*)WrL;
    for (int i = tid; i < 8192; i += 512) dst[i] = src[i];
  }
  if (tid < 2) { ncLo[tid] = 0; ncHi[tid] = 0; }
  __syncthreads();

  float mr = 0.f, sr_own = 0.f;
  const int g = tid >> 7;        // 0..3
  const int c = tid & 127;       // dword column

  for (int t = 0; t < T_; t++) {
    const int old = t & 1, nxt = old ^ 1;
    float c2 = cur2a[((size_t)t * B_ + b) * H2_ + tid];
    if (tid == 510) ncLo[nxt] = 0;
    if (tid == 511) ncHi[nxt] = 0;
    const int nLo = ncLo[old];
    const int nHi = ncHi[old];
    const int* LLo = lstLo[old];
    const int* LHi = lstHi[old];

    int a4[4] = {0, 0, 0, 0};
    // ---- LDS-resident half (rows < 256), spikes k == g (mod 4) ----
    {
      int k = g;
      for (; k + 28 < nLo; k += 32) {
        int i0 = LLo[k],      i1 = LLo[k + 4],  i2 = LLo[k + 8],  i3 = LLo[k + 12];
        int i4 = LLo[k + 16], i5 = LLo[k + 20], i6 = LLo[k + 24], i7 = LLo[k + 28];
        unsigned w0 = WrL[(i0 << 7) + c], w1 = WrL[(i1 << 7) + c];
        unsigned w2 = WrL[(i2 << 7) + c], w3 = WrL[(i3 << 7) + c];
        unsigned w4 = WrL[(i4 << 7) + c], w5 = WrL[(i5 << 7) + c];
        unsigned w6 = WrL[(i6 << 7) + c], w7 = WrL[(i7 << 7) + c];
        unp_add(w0, a4); unp_add(w1, a4); unp_add(w2, a4); unp_add(w3, a4);
        unp_add(w4, a4); unp_add(w5, a4); unp_add(w6, a4); unp_add(w7, a4);
      }
      for (; k + 12 < nLo; k += 16) {
        int i0 = LLo[k], i1 = LLo[k + 4], i2 = LLo[k + 8], i3 = LLo[k + 12];
        unsigned w0 = WrL[(i0 << 7) + c], w1 = WrL[(i1 << 7) + c];
        unsigned w2 = WrL[(i2 << 7) + c], w3 = WrL[(i3 << 7) + c];
        unp_add(w0, a4); unp_add(w1, a4); unp_add(w2, a4); unp_add(w3, a4);
      }
      for (; k < nLo; k += 4) unp_add(WrL[(LLo[k] << 7) + c], a4);
    }
    // ---- global half (rows >= 256) ----
    {
      int k = g;
      for (; k + 28 < nHi; k += 32) {
        int i0 = LHi[k],      i1 = LHi[k + 4],  i2 = LHi[k + 8],  i3 = LHi[k + 12];
        int i4 = LHi[k + 16], i5 = LHi[k + 20], i6 = LHi[k + 24], i7 = LHi[k + 28];
        unsigned w0 = WrT4[(i0 << 7) + c], w1 = WrT4[(i1 << 7) + c];
        unsigned w2 = WrT4[(i2 << 7) + c], w3 = WrT4[(i3 << 7) + c];
        unsigned w4 = WrT4[(i4 << 7) + c], w5 = WrT4[(i5 << 7) + c];
        unsigned w6 = WrT4[(i6 << 7) + c], w7 = WrT4[(i7 << 7) + c];
        unp_add(w0, a4); unp_add(w1, a4); unp_add(w2, a4); unp_add(w3, a4);
        unp_add(w4, a4); unp_add(w5, a4); unp_add(w6, a4); unp_add(w7, a4);
      }
      for (; k + 12 < nHi; k += 16) {
        int i0 = LHi[k], i1 = LHi[k + 4], i2 = LHi[k + 8], i3 = LHi[k + 12];
        unsigned w0 = WrT4[(i0 << 7) + c], w1 = WrT4[(i1 << 7) + c];
        unsigned w2 = WrT4[(i2 << 7) + c], w3 = WrT4[(i3 << 7) + c];
        unp_add(w0, a4); unp_add(w1, a4); unp_add(w2, a4); unp_add(w3, a4);
      }
      for (; k < nHi; k += 4) unp_add(WrT4[(LHi[k] << 7) + c], a4);
    }
    *(int4*)&red[g][c << 2] = make_int4(a4[0], a4[1], a4[2], a4[3]);
    __syncthreads();                               // S1

    {
      int acc = red[0][tid] + red[1][tid] + red[2][tid] + red[3][tid];
      float h = s2sc * c2 + srsc * (float)acc;
      mr = (br * mr + h) * (1.f - sr_own);
      sr_own = (mr - thr > 0.f) ? 1.f : 0.f;
      sru[((size_t)t * B_ + b) * H2_ + tid] = (unsigned char)(sr_own != 0.f);
    }
    bool spike = (sr_own != 0.f);
    unsigned long long bm = __ballot(spike);
    if (bm != 0ull) {
      const int lane = tid & 63;
      const int ldr = (int)__ffsll((long long)bm) - 1;
      int* cnt = (tid < 256) ? &ncLo[nxt] : &ncHi[nxt];   // wave-uniform choice
      int* dst = (tid < 256) ? lstLo[nxt] : lstHi[nxt];
      int base = 0;
      if (lane == ldr) base = atomicAdd(cnt, (int)__popcll(bm));
      base = __shfl(base, ldr);
      if (spike)
        dst[base + (int)__popcll(bm & ((1ull << lane) - 1ull))] = tid;
    }
    __syncthreads();                               // S2
  }
}

// ---------------------------------------------------------------------------
// scan3: parallel layer-2 LIF scan (op order unchanged), unroll 8.
// ---------------------------------------------------------------------------
__global__ __launch_bounds__(256) void scan3_k(const float* __restrict__ cur3,
                                               float* __restrict__ out,
                                               const float* __restrict__ scales,
                                               const float* __restrict__ beta2p,
                                               const float* __restrict__ th2p) {
  const int n = blockIdx.x * 256 + threadIdx.x;
  const float s3sc = scales[3];
  const float b2 = fminf(fmaxf(beta2p[0], 0.f), 1.f);
  const float th2 = th2p[0];
  const size_t S = (size_t)B_ * OUT_;
  float m2 = 0.f;
  for (int t = 0; t < T_; t += 8) {
    float v[8];
#pragma unroll
    for (int j = 0; j < 8; j++) v[j] = cur3[(size_t)(t + j) * S + n];
#pragma unroll
    for (int j = 0; j < 8; j++) {
      m2 = b2 * m2 + s3sc * v[j];
      float p = (m2 - th2 > 0.f) ? 1.f : 0.f;
      m2 *= (1.f - p);
      out[(size_t)(t + j) * S + n] = p;
    }
  }
}

// ---------------------------------------------------------------------------
extern "C" void kernel_launch(void* const* d_in, const int* in_sizes, int n_in,
                              void* d_out, int out_size, void* d_ws, size_t ws_size,
                              hipStream_t stream) {
  const float* data  = (const float*)d_in[0];
  const float* W1    = (const float*)d_in[1];
  const float* W2    = (const float*)d_in[2];
  const float* Wr    = (const float*)d_in[3];
  const float* W3    = (const float*)d_in[4];
  const float* beta1 = (const float*)d_in[5];
  const float* th1   = (const float*)d_in[6];
  const float* betar = (const float*)d_in[7];
  const float* thr   = (const float*)d_in[8];
  const float* beta2 = (const float*)d_in[9];
  const float* th2   = (const float*)d_in[10];

  char* ws = (char*)d_ws;
  float*         scales = (float*)ws;                                   // @0 (16 B)
  unsigned*      smax   = (unsigned*)(ws + 64);                         // @64 (16 B)
  float*         W1qT   = (float*)(ws + 4096);                          // 1 MB [NIN][H1]
  signed char*   W2i8   = (signed char*)(ws + 4096 + 1048576);          // 256 KB [H2][H1]
  signed char*   W3i8   = (signed char*)(ws + 4096 + 1048576 + 524288); // 64 KB [OUT][H2]
  signed char*   WrT    = (signed char*)(ws + 4096 + 1048576 + 524288 + 131072); // 256 KB
  // region A (128 MB): cur1 -> cur2a -> cur3 (sequential lifetimes)
  float*         regA   = (float*)(ws + (size_t)4194304);
  // region B (64 MB): s1u + sru
  unsigned char* regB   = (unsigned char*)(ws + (size_t)4194304 + 134217728);

  float* cur1  = regA;
  float* cur2a = regA;
  float* cur3  = regA;
  unsigned char* s1u = regB;
  unsigned char* sru = regB + (size_t)33554432;

  hipMemsetAsync(smax, 0, 16, stream);
  hipLaunchKernelGGL(absmax_k, dim3(256), dim3(256), 0, stream, W1, W2, Wr, W3, smax);
  hipLaunchKernelGGL(quant_all_k, dim3(3328), dim3(256), 0, stream,
                     W1, W2, Wr, W3, smax, scales, W1qT, W2i8, WrT, W3i8);

  hipLaunchKernelGGL(gemm_cur1_k, dim3(8, 256), dim3(512), 0, stream, data, W1qT, cur1);
  hipLaunchKernelGGL(scan1_k, dim3((B_ * H1_) / 256), dim3(256), 0, stream, cur1, s1u, beta1, th1);
  hipLaunchKernelGGL(gemm_spk_k, dim3(512, 4), dim3(256), 0, stream, s1u, W2i8, cur2a, H2_);
  hipLaunchKernelGGL(recurrent_k, dim3(256), dim3(512), 0, stream, cur2a, WrT, sru, scales, betar, thr);
  hipLaunchKernelGGL(gemm_spk_k, dim3(512, 1), dim3(256), 0, stream, sru, W3i8, cur3, OUT_);
  hipLaunchKernelGGL(scan3_k, dim3((B_ * OUT_) / 256), dim3(256), 0, stream, cur3, (float*)d_out, scales, beta2, th2);
}

// Round 10
// 987.448 us; speedup vs baseline: 1.0186x; 1.0167x over previous
//
#include <hip/hip_runtime.h>

#define B_   256
#define NIN_ 512
#define T_   256
#define H1_  512
#define H2_  512
#define OUT_ 128

typedef __attribute__((ext_vector_type(4))) int i32x4;
typedef __attribute__((address_space(1))) const unsigned int* gl_cu;
typedef __attribute__((address_space(3))) unsigned int* ls_u;

// ---------------------------------------------------------------------------
// Per-tensor absmax, parallel: 64 blocks per tensor, atomicMax on uint bits
// (valid: all values are fabs() >= 0; IEEE non-negative floats order as uints).
// smax[] zeroed by hipMemsetAsync.  Max is order-independent -> same scale.
// ---------------------------------------------------------------------------
__global__ __launch_bounds__(256) void absmax_k(const float* __restrict__ W1,
                                                const float* __restrict__ W2,
                                                const float* __restrict__ Wr,
                                                const float* __restrict__ W3,
                                                unsigned* __restrict__ smax) {
  const int tens = blockIdx.x >> 6;   // 0..3
  const int sub  = blockIdx.x & 63;
  const float* W; int n4;
  switch (tens) {
    case 0:  W = W1; n4 = (H1_ * NIN_) >> 2; break;
    case 1:  W = W2; n4 = (H2_ * H1_) >> 2;  break;
    case 2:  W = Wr; n4 = (H2_ * H2_) >> 2;  break;
    default: W = W3; n4 = (OUT_ * H2_) >> 2; break;
  }
  const int per = n4 >> 6;            // 1024 (W1/W2/Wr) or 256 (W3)
  const float4* W4 = (const float4*)W + sub * per;
  int tid = threadIdx.x;
  float m = 0.f;
  for (int i = tid; i < per; i += 256) {
    float4 v = W4[i];
    m = fmaxf(m, fmaxf(fmaxf(fabsf(v.x), fabsf(v.y)), fmaxf(fabsf(v.z), fabsf(v.w))));
  }
  __shared__ float red[256];
  red[tid] = m;
  __syncthreads();
  for (int s = 128; s > 0; s >>= 1) {
    if (tid < s) red[tid] = fmaxf(red[tid], red[tid + s]);
    __syncthreads();
  }
  if (tid == 0) atomicMax(smax + tens, __float_as_uint(red[0]));
}

// ---------------------------------------------------------------------------
// Fused quantization of all four weight tensors (one launch).
//  blocks 0..1023    : W1 -> fp32 q*s, transposed [NIN][H1]    (W1qT)
//  blocks 1024..2047 : W2 -> int8 q, row-major [H2][H1]        (W2i8)
//  blocks 2048..3071 : Wr -> int8 q, presyn-major [H2][H2]     (WrT, transposed)
//  blocks 3072..3327 : W3 -> int8 q, row-major [OUT][H2]       (W3i8)
// ---------------------------------------------------------------------------
__global__ void quant_all_k(const float* __restrict__ W1, const float* __restrict__ W2,
                            const float* __restrict__ Wr, const float* __restrict__ W3,
                            const unsigned* __restrict__ smax,
                            float* __restrict__ scales,
                            float* __restrict__ W1qT, signed char* __restrict__ W2i8,
                            signed char* __restrict__ WrT, signed char* __restrict__ W3i8) {
  const int blk = blockIdx.x;
  if (blk == 0 && threadIdx.x < 4)
    scales[threadIdx.x] = __uint_as_float(smax[threadIdx.x]) / 127.0f;
  if (blk < 1024) {
    int idx = blk * 256 + threadIdx.x;
    int h = idx & (H1_ - 1), i = idx >> 9;
    float s = __uint_as_float(smax[0]) / 127.0f;
    float q = rintf(W1[h * NIN_ + i] / s);
    q = fminf(fmaxf(q, -127.f), 127.f);
    W1qT[idx] = q * s;
  } else if (blk < 2048) {
    int idx = (blk - 1024) * 256 + threadIdx.x;
    float s = __uint_as_float(smax[1]) / 127.0f;
    float q = rintf(W2[idx] / s);
    q = fminf(fmaxf(q, -127.f), 127.f);
    W2i8[idx] = (signed char)q;
  } else if (blk < 3072) {
    int idx = (blk - 2048) * 256 + threadIdx.x;
    int r = idx >> 9, c = idx & (H2_ - 1);
    float s = __uint_as_float(smax[2]) / 127.0f;
    float q = rintf(Wr[idx] / s);
    q = fminf(fmaxf(q, -127.f), 127.f);
    WrT[(size_t)c * H2_ + r] = (signed char)q;
  } else {
    int idx = (blk - 3072) * 256 + threadIdx.x;
    float s = __uint_as_float(smax[3]) / 127.0f;
    float q = rintf(W3[idx] / s);
    q = fminf(fmaxf(q, -127.f), 127.f);
    W3i8[idx] = (signed char)q;
  }
}

// ---------------------------------------------------------------------------
// Phase A: cur1[t,b,h] = sum_i data[b,i,t] * W1qT[i,h].  fp32.
// ROUND-2 VERIFIED STRUCTURE, PARKED at ~385-392 us (56% fp32 peak).
// FMA order: per output element a single accumulator over k ascending
// 0..511 -> bit-identical cur1.  GOLDEN arithmetic preserved.
// ---------------------------------------------------------------------------
__global__ __launch_bounds__(512, 6) void gemm_cur1_k(const float* __restrict__ data,
                                                      const float* __restrict__ W1qT,
                                                      float* __restrict__ cur1) {
  const int b  = blockIdx.y;
  const int t0 = (blockIdx.x >> 2) << 7;
  const int h0 = (blockIdx.x & 3) << 7;
  const int tid = threadIdx.x;

  __shared__ float As[2][16][128];   // 16 KB
  __shared__ float Bs[2][16][128];   // 16 KB

  const int ty = tid >> 4, tx = tid & 15;   // ty 0..31, tx 0..15
  const int wv = tid >> 6;                  // 0..7
  const int ln = tid & 63;

  float acc[4][8];
#pragma unroll
  for (int i = 0; i < 4; i++)
#pragma unroll
    for (int j = 0; j < 8; j++) acc[i][j] = 0.f;

  const float* dbase = data + (size_t)b * NIN_ * T_;

  auto issue = [&](int kb, int buf) {
    const int kr = (wv << 1) + (ln >> 5);
    const float* ga = dbase + (size_t)(kb + kr) * T_ + t0 + ((ln & 31) << 2);
    __builtin_amdgcn_global_load_lds((gl_cu)ga, (ls_u)&As[buf][wv << 1][0], 16, 0, 0);
    const float* gb = W1qT + (size_t)(kb + kr) * H1_ + h0 + ((ln & 31) << 2);
    __builtin_amdgcn_global_load_lds((gl_cu)gb, (ls_u)&Bs[buf][wv << 1][0], 16, 0, 0);
  };

  issue(0, 0);

  for (int p = 0; p < 32; p++) {
    const int cur = p & 1;
    __syncthreads();
    if (p < 31) issue((p + 1) << 4, cur ^ 1);
#pragma unroll
    for (int k = 0; k < 16; k++) {
      float4 A0 = *(const float4*)&As[cur][k][ty * 4];
      float4 B0 = *(const float4*)&Bs[cur][k][tx * 4];
      float4 B1 = *(const float4*)&Bs[cur][k][64 + tx * 4];
      float a[4] = {A0.x, A0.y, A0.z, A0.w};
      float w[8] = {B0.x, B0.y, B0.z, B0.w, B1.x, B1.y, B1.z, B1.w};
#pragma unroll
      for (int i = 0; i < 4; i++)
#pragma unroll
        for (int j = 0; j < 8; j++)
          acc[i][j] = fmaf(a[i], w[j], acc[i][j]);
    }
  }

#pragma unroll
  for (int i = 0; i < 4; i++) {
    int row = ty * 4 + i;
    float* op = cur1 + (size_t)(t0 + row) * (B_ * H1_) + (size_t)b * H1_ + h0;
    float4 cA = {acc[i][0], acc[i][1], acc[i][2], acc[i][3]};
    float4 cB = {acc[i][4], acc[i][5], acc[i][6], acc[i][7]};
    *(float4*)(op + tx * 4)      = cA;
    *(float4*)(op + 64 + tx * 4) = cB;
  }
}

// ---------------------------------------------------------------------------
// scan1: parallel per-neuron layer-1 LIF scan (op order unchanged), unroll 8.
// ---------------------------------------------------------------------------
__global__ __launch_bounds__(256) void scan1_k(const float* __restrict__ cur1,
                                               unsigned char* __restrict__ s1u,
                                               const float* __restrict__ beta1p,
                                               const float* __restrict__ th1p) {
  const int n = blockIdx.x * 256 + threadIdx.x;
  const float b1 = fminf(fmaxf(beta1p[0], 0.f), 1.f);
  const float th1 = th1p[0];
  const size_t S = (size_t)B_ * H1_;
  float m1 = 0.f;
  for (int t = 0; t < T_; t += 8) {
    float c[8];
#pragma unroll
    for (int j = 0; j < 8; j++) c[j] = cur1[(size_t)(t + j) * S + n];
#pragma unroll
    for (int j = 0; j < 8; j++) {
      m1 = b1 * m1 + c[j];
      bool s = m1 - th1 > 0.f;
      if (s) m1 = 0.f;
      s1u[(size_t)(t + j) * S + n] = s;
    }
  }
}

// ---------------------------------------------------------------------------
// Spike GEMM via i8 MFMA (exact integer sums, i32 accumulate).  VERIFIED.
// Double-buffered LDS, one barrier per K-block; m-tile on blockIdx.x.
// ---------------------------------------------------------------------------
__global__ __launch_bounds__(256) void gemm_spk_k(const unsigned char* __restrict__ A8,
                                                  const signed char* __restrict__ Bw,
                                                  float* __restrict__ C, int N) {
  __shared__ __align__(16) signed char As[2][128 * 80];   // 20 KB
  __shared__ __align__(16) signed char Bs[2][128 * 80];   // 20 KB
  const int tid = threadIdx.x;
  const int m0 = blockIdx.x << 7;
  const int n0 = blockIdx.y << 7;
  const int lane = tid & 63, wave = tid >> 6;
  const int quad = lane >> 4, lm = lane & 15;
  const int wm = wave << 5;

  i32x4 acc[2][8];
#pragma unroll
  for (int s = 0; s < 2; s++)
#pragma unroll
    for (int n = 0; n < 8; n++) acc[s][n] = (i32x4){0, 0, 0, 0};

  const int row = tid >> 2;            // 0..63 (+64 on second pass)
  const int offB = (tid & 3) << 4;     // 0/16/32/48 within 64-byte k-window

  uint4 av[2], bv[2];
  auto gload = [&](int kb) {
#pragma unroll
    for (int i = 0; i < 2; i++) {
      const int r = row + (i << 6);
      av[i] = *(const uint4*)(A8 + (size_t)(m0 + r) * 512 + kb + offB);
      bv[i] = *(const uint4*)(Bw + (size_t)(n0 + r) * 512 + kb + offB);
    }
  };

  gload(0);
  int buf = 0;
  for (int kb8 = 0; kb8 < 8; kb8++) {
#pragma unroll
    for (int i = 0; i < 2; i++) {
      const int r = row + (i << 6);
      *(uint4*)&As[buf][r * 80 + offB] = av[i];
      *(uint4*)&Bs[buf][r * 80 + offB] = bv[i];
    }
    __syncthreads();
    if (kb8 < 7) gload((kb8 + 1) << 6);   // overlaps with MFMAs below
    i32x4 a0 = *(const i32x4*)&As[buf][(wm + lm) * 80 + (quad << 4)];
    i32x4 a1 = *(const i32x4*)&As[buf][(wm + 16 + lm) * 80 + (quad << 4)];
    i32x4 bq[8];
#pragma unroll
    for (int n = 0; n < 8; n++)
      bq[n] = *(const i32x4*)&Bs[buf][((n << 4) + lm) * 80 + (quad << 4)];
#pragma unroll
    for (int n = 0; n < 8; n++) {
      acc[0][n] = __builtin_amdgcn_mfma_i32_16x16x64_i8(a0, bq[n], acc[0][n], 0, 0, 0);
      acc[1][n] = __builtin_amdgcn_mfma_i32_16x16x64_i8(a1, bq[n], acc[1][n], 0, 0, 0);
    }
    buf ^= 1;
  }

#pragma unroll
  for (int s = 0; s < 2; s++)
#pragma unroll
    for (int n = 0; n < 8; n++) {
      int orow = m0 + wm + (s << 4) + quad * 4;
      int col = n0 + (n << 4) + lm;
#pragma unroll
      for (int r = 0; r < 4; r++)
        C[(size_t)(orow + r) * N + col] = (float)acc[s][n][r];
    }
}

// ---------------------------------------------------------------------------
__device__ __forceinline__ void unp_add(unsigned w, int* a) {
  int iw = (int)w;
  a[0] += (iw << 24) >> 24;
  a[1] += (iw << 16) >> 24;
  a[2] += (iw << 8) >> 24;
  a[3] += iw >> 24;
}

// ---------------------------------------------------------------------------
// Sequential recurrent layer.  One block per batch row, 1024 threads.
// ROUND-7 VERIFIED FORM (session best, 985 us total).  Both structural
// variants regressed: round-8 prefetch+lgkm-barriers (+21 us), round-9
// 512-thread (+25 us).  Floor is the 256-step serial dependency.
// ---------------------------------------------------------------------------
__global__ __launch_bounds__(1024) void recurrent_k(
    const float* __restrict__ cur2a,       // [T*B, H2]
    const signed char* __restrict__ WrT,   // [H2][H2] presyn-major
    unsigned char* __restrict__ sru,       // [T*B, H2]
    const float* __restrict__ scales,
    const float* __restrict__ betarp, const float* __restrict__ thrp) {
  const int b = blockIdx.x;
  const int tid = threadIdx.x;
  const float s2sc = scales[1];
  const float srsc = scales[2];
  const float br = fminf(fmaxf(betarp[0], 0.f), 1.f);
  const float thr = thrp[0];

  const unsigned* WrT4 = (const unsigned*)WrT;   // [H2][128] dwords

  __shared__ unsigned WrL[256 * 128];   // 128 KB: presyn rows 0..255
  __shared__ int red[8][H2_];           // 16 KB
  __shared__ int lstLo[2][256];         // 2 KB
  __shared__ int lstHi[2][256];         // 2 KB
  __shared__ int ncLo[2], ncHi[2];

  {
    const uint4* src = (const uint4*)WrT4;
    uint4* dst = (uint4*)WrL;
    for (int i = tid; i < 8192; i += 1024) dst[i] = src[i];
  }
  if (tid < 2) { ncLo[tid] = 0; ncHi[tid] = 0; }
  __syncthreads();

  float mr = 0.f, sr_own = 0.f;
  const int g = tid >> 7;        // 0..7
  const int c = tid & 127;       // dword column

  for (int t = 0; t < T_; t++) {
    const int old = t & 1, nxt = old ^ 1;
    float c2 = 0.f;
    if (tid < H2_) c2 = cur2a[((size_t)t * B_ + b) * H2_ + tid];
    if (tid == 1022) ncLo[nxt] = 0;
    if (tid == 1023) ncHi[nxt] = 0;
    const int nLo = ncLo[old];
    const int nHi = ncHi[old];
    const int* LLo = lstLo[old];
    const int* LHi = lstHi[old];

    int a4[4] = {0, 0, 0, 0};
    // ---- LDS-resident half (rows < 256) ----
    {
      int k = g;
      for (; k + 56 < nLo; k += 64) {
        int i0 = LLo[k],      i1 = LLo[k + 8],  i2 = LLo[k + 16], i3 = LLo[k + 24];
        int i4 = LLo[k + 32], i5 = LLo[k + 40], i6 = LLo[k + 48], i7 = LLo[k + 56];
        unsigned w0 = WrL[(i0 << 7) + c], w1 = WrL[(i1 << 7) + c];
        unsigned w2 = WrL[(i2 << 7) + c], w3 = WrL[(i3 << 7) + c];
        unsigned w4 = WrL[(i4 << 7) + c], w5 = WrL[(i5 << 7) + c];
        unsigned w6 = WrL[(i6 << 7) + c], w7 = WrL[(i7 << 7) + c];
        unp_add(w0, a4); unp_add(w1, a4); unp_add(w2, a4); unp_add(w3, a4);
        unp_add(w4, a4); unp_add(w5, a4); unp_add(w6, a4); unp_add(w7, a4);
      }
      for (; k + 24 < nLo; k += 32) {
        int i0 = LLo[k], i1 = LLo[k + 8], i2 = LLo[k + 16], i3 = LLo[k + 24];
        unsigned w0 = WrL[(i0 << 7) + c], w1 = WrL[(i1 << 7) + c];
        unsigned w2 = WrL[(i2 << 7) + c], w3 = WrL[(i3 << 7) + c];
        unp_add(w0, a4); unp_add(w1, a4); unp_add(w2, a4); unp_add(w3, a4);
      }
      for (; k < nLo; k += 8) unp_add(WrL[(LLo[k] << 7) + c], a4);
    }
    // ---- global half (rows >= 256) ----
    {
      int k = g;
      for (; k + 56 < nHi; k += 64) {
        int i0 = LHi[k],      i1 = LHi[k + 8],  i2 = LHi[k + 16], i3 = LHi[k + 24];
        int i4 = LHi[k + 32], i5 = LHi[k + 40], i6 = LHi[k + 48], i7 = LHi[k + 56];
        unsigned w0 = WrT4[(i0 << 7) + c], w1 = WrT4[(i1 << 7) + c];
        unsigned w2 = WrT4[(i2 << 7) + c], w3 = WrT4[(i3 << 7) + c];
        unsigned w4 = WrT4[(i4 << 7) + c], w5 = WrT4[(i5 << 7) + c];
        unsigned w6 = WrT4[(i6 << 7) + c], w7 = WrT4[(i7 << 7) + c];
        unp_add(w0, a4); unp_add(w1, a4); unp_add(w2, a4); unp_add(w3, a4);
        unp_add(w4, a4); unp_add(w5, a4); unp_add(w6, a4); unp_add(w7, a4);
      }
      for (; k + 24 < nHi; k += 32) {
        int i0 = LHi[k], i1 = LHi[k + 8], i2 = LHi[k + 16], i3 = LHi[k + 24];
        unsigned w0 = WrT4[(i0 << 7) + c], w1 = WrT4[(i1 << 7) + c];
        unsigned w2 = WrT4[(i2 << 7) + c], w3 = WrT4[(i3 << 7) + c];
        unp_add(w0, a4); unp_add(w1, a4); unp_add(w2, a4); unp_add(w3, a4);
      }
      for (; k < nHi; k += 8) unp_add(WrT4[(LHi[k] << 7) + c], a4);
    }
    *(int4*)&red[g][c << 2] = make_int4(a4[0], a4[1], a4[2], a4[3]);
    __syncthreads();                               // S1

    bool spike = false;
    if (tid < H2_) {
      int acc = red[0][tid] + red[1][tid] + red[2][tid] + red[3][tid]
              + red[4][tid] + red[5][tid] + red[6][tid] + red[7][tid];
      float h = s2sc * c2 + srsc * (float)acc;
      mr = (br * mr + h) * (1.f - sr_own);
      sr_own = (mr - thr > 0.f) ? 1.f : 0.f;
      sru[((size_t)t * B_ + b) * H2_ + tid] = (unsigned char)(sr_own != 0.f);
      spike = (sr_own != 0.f);
    }
    unsigned long long bm = __ballot(spike);
    if (bm != 0ull) {
      const int lane = tid & 63;
      const int ldr = (int)__ffsll((long long)bm) - 1;
      int* cnt = (tid < 256) ? &ncLo[nxt] : &ncHi[nxt];   // wave-uniform choice
      int* dst = (tid < 256) ? lstLo[nxt] : lstHi[nxt];
      int base = 0;
      if (lane == ldr) base = atomicAdd(cnt, (int)__popcll(bm));
      base = __shfl(base, ldr);
      if (spike)
        dst[base + (int)__popcll(bm & ((1ull << lane) - 1ull))] = tid;
    }
    __syncthreads();                               // S2
  }
}

// ---------------------------------------------------------------------------
// scan3: parallel layer-2 LIF scan (op order unchanged), unroll 8.
// ---------------------------------------------------------------------------
__global__ __launch_bounds__(256) void scan3_k(const float* __restrict__ cur3,
                                               float* __restrict__ out,
                                               const float* __restrict__ scales,
                                               const float* __restrict__ beta2p,
                                               const float* __restrict__ th2p) {
  const int n = blockIdx.x * 256 + threadIdx.x;
  const float s3sc = scales[3];
  const float b2 = fminf(fmaxf(beta2p[0], 0.f), 1.f);
  const float th2 = th2p[0];
  const size_t S = (size_t)B_ * OUT_;
  float m2 = 0.f;
  for (int t = 0; t < T_; t += 8) {
    float v[8];
#pragma unroll
    for (int j = 0; j < 8; j++) v[j] = cur3[(size_t)(t + j) * S + n];
#pragma unroll
    for (int j = 0; j < 8; j++) {
      m2 = b2 * m2 + s3sc * v[j];
      float p = (m2 - th2 > 0.f) ? 1.f : 0.f;
      m2 *= (1.f - p);
      out[(size_t)(t + j) * S + n] = p;
    }
  }
}

// ---------------------------------------------------------------------------
extern "C" void kernel_launch(void* const* d_in, const int* in_sizes, int n_in,
                              void* d_out, int out_size, void* d_ws, size_t ws_size,
                              hipStream_t stream) {
  const float* data  = (const float*)d_in[0];
  const float* W1    = (const float*)d_in[1];
  const float* W2    = (const float*)d_in[2];
  const float* Wr    = (const float*)d_in[3];
  const float* W3    = (const float*)d_in[4];
  const float* beta1 = (const float*)d_in[5];
  const float* th1   = (const float*)d_in[6];
  const float* betar = (const float*)d_in[7];
  const float* thr   = (const float*)d_in[8];
  const float* beta2 = (const float*)d_in[9];
  const float* th2   = (const float*)d_in[10];

  char* ws = (char*)d_ws;
  float*         scales = (float*)ws;                                   // @0 (16 B)
  unsigned*      smax   = (unsigned*)(ws + 64);                         // @64 (16 B)
  float*         W1qT   = (float*)(ws + 4096);                          // 1 MB [NIN][H1]
  signed char*   W2i8   = (signed char*)(ws + 4096 + 1048576);          // 256 KB [H2][H1]
  signed char*   W3i8   = (signed char*)(ws + 4096 + 1048576 + 524288); // 64 KB [OUT][H2]
  signed char*   WrT    = (signed char*)(ws + 4096 + 1048576 + 524288 + 131072); // 256 KB
  // region A (128 MB): cur1 -> cur2a -> cur3 (sequential lifetimes)
  float*         regA   = (float*)(ws + (size_t)4194304);
  // region B (64 MB): s1u + sru
  unsigned char* regB   = (unsigned char*)(ws + (size_t)4194304 + 134217728);

  float* cur1  = regA;
  float* cur2a = regA;
  float* cur3  = regA;
  unsigned char* s1u = regB;
  unsigned char* sru = regB + (size_t)33554432;

  hipMemsetAsync(smax, 0, 16, stream);
  hipLaunchKernelGGL(absmax_k, dim3(256), dim3(256), 0, stream, W1, W2, Wr, W3, smax);
  hipLaunchKernelGGL(quant_all_k, dim3(3328), dim3(256), 0, stream,
                     W1, W2, Wr, W3, smax, scales, W1qT, W2i8, WrT, W3i8);

  hipLaunchKernelGGL(gemm_cur1_k, dim3(8, 256), dim3(512), 0, stream, data, W1qT, cur1);
  hipLaunchKernelGGL(scan1_k, dim3((B_ * H1_) / 256), dim3(256), 0, stream, cur1, s1u, beta1, th1);
  hipLaunchKernelGGL(gemm_spk_k, dim3(512, 4), dim3(256), 0, stream, s1u, W2i8, cur2a, H2_);
  hipLaunchKernelGGL(recurrent_k, dim3(256), dim3(1024), 0, stream, cur2a, WrT, sru, scales, betar, thr);
  hipLaunchKernelGGL(gemm_spk_k, dim3(512, 1), dim3(256), 0, stream, sru, W3i8, cur3, OUT_);
  hipLaunchKernelGGL(scan3_k, dim3((B_ * OUT_) / 256), dim3(256), 0, stream, cur3, (float*)d_out, scales, beta2, th2);
}